// Round 14
// baseline (97.529 us; speedup 1.0000x reference)
//
#include <hip/hip_runtime.h>

#define NN 512
#define DD 64
#define FN 32
#define AP 520               // bf16 pitch (1040 B): b128 reads conflict-free, us4 writes 2-way

typedef unsigned short ushortT;
typedef __attribute__((ext_vector_type(4))) unsigned short us4;
typedef __attribute__((ext_vector_type(8))) short s8;     // 8 bf16 MFMA operand
typedef __attribute__((ext_vector_type(4))) float f4;     // MFMA accumulator

__device__ inline ushortT f2bf(float x) {
    unsigned u = __float_as_uint(x);
    return (ushortT)((u + 0x7FFFu + ((u >> 16) & 1u)) >> 16);   // RNE
}

// ---------------- Single fused kernel ----------------
// 256 blocks x 512 thr (8 waves). b = bid&15 (XCD-affine: 16 blocks of a batch share an L2),
// m = bid>>4. Block owns rows [b*512 + 32m, +32). LDS 119 KB; T (f32 transpose scratch)
// aliases adjS, so phase A2 (prev) runs before phase A1 (adj stream).
__global__ __launch_bounds__(512) void fused_kernel(
    const float* __restrict__ prev, const float* __restrict__ adj,
    const float* __restrict__ nf,   const float* __restrict__ ef,
    const float* __restrict__ W1,   const float* __restrict__ W2,
    const float* __restrict__ W3,   const float* __restrict__ W4,
    float* __restrict__ out)
{
    __shared__ __align__(16) char lds[119168];
    ushortT* prevS = (ushortT*)(lds);            // 64 x 520 bf16 = 66560 B
    ushortT* adjS  = (ushortT*)(lds + 66560);    // 32 x 520 bf16 = 33280 B
    float*   T     = (float*)  (lds + 66560);    // alias: f32 [128][65] = 33280 B
    ushortT* PT    = (ushortT*)(lds + 99840);    // 32 x 72 bf16 = 4608 B
    ushortT* W2S   = (ushortT*)(lds + 104448);   // 64 x 64 = 8192 B
    ushortT* W1S   = (ushortT*)(lds + 112640);   // 64 x 32 = 4096 B
    float*   vpart = (float*)  (lds + 116736);   // [8][64] f32 = 2048 B
    float*   v3S   = (float*)  (lds + 118784);   // 64 f32
    float*   tsum  = (float*)  (lds + 119040);   // 32 f32

    const int tid  = threadIdx.x;
    const int lane = tid & 63;
    const int wv   = __builtin_amdgcn_readfirstlane(tid >> 6);  // 0..7
    const int bid  = blockIdx.x;
    const int b    = bid & 15;           // batch (XCD-affine)
    const int m    = bid >> 4;           // 32-row group within batch
    const int i0   = b * NN + m * 32;    // global row base
    const int l15  = lane & 15, g = lane >> 4;
    const int rh   = wv >> 2, nt = wv & 3;

    // ---- phase A2: prev[b] -> prevS transposed bf16, via padded f32 T (conflict-free)
    const float* pbase = prev + b * NN * DD;
    for (int c = 0; c < 4; ++c) {                    // 128-j chunks
        const float4* src = (const float4*)(pbase + c * 128 * DD);
        #pragma unroll
        for (int s2 = 0; s2 < 4; ++s2) {             // coalesced f32 -> T[jl][d]
            int fi = s2 * 512 + tid;                 // 0..2047
            int jl = fi >> 4, d4 = (fi & 15) * 4;
            float4 v = src[fi];
            float* dst = &T[jl * 65 + d4];
            dst[0] = v.x; dst[1] = v.y; dst[2] = v.z; dst[3] = v.w;
        }
        __syncthreads();
        #pragma unroll
        for (int s3 = 0; s3 < 4; ++s3) {             // strided read (pad 65 => bank-spread)
            int o = s3 * 512 + tid;                  // 0..2047
            int dcol = o & 63, j4 = (o >> 6) * 4;    // j4: 0..124
            us4 ov = { f2bf(T[(j4 + 0) * 65 + dcol]), f2bf(T[(j4 + 1) * 65 + dcol]),
                       f2bf(T[(j4 + 2) * 65 + dcol]), f2bf(T[(j4 + 3) * 65 + dcol]) };
            *(us4*)(&prevS[dcol * AP + c * 128 + j4]) = ov;
        }
        __syncthreads();
    }

    // ---- phase A1: adj/ef stream -> t + adjS (adjS region now free)
    {
        const int r = tid >> 4, c16 = tid & 15;
        const float4* ag = (const float4*)(adj + (i0 + r) * NN + c16 * 32);
        const float4* eg = (const float4*)(ef  + (i0 + r) * NN + c16 * 32);
        float tp = 0.f;
        #pragma unroll
        for (int it = 0; it < 8; ++it) {
            float4 av = ag[it], ev = eg[it];
            tp += av.x*ev.x + av.y*ev.y + av.z*ev.z + av.w*ev.w;
            us4 ov = { f2bf(av.x), f2bf(av.y), f2bf(av.z), f2bf(av.w) };
            *(us4*)(&adjS[r * AP + c16 * 32 + it * 4]) = ov;
        }
        tp += __shfl_xor(tp, 1, 64);
        tp += __shfl_xor(tp, 2, 64);
        tp += __shfl_xor(tp, 4, 64);
        tp += __shfl_xor(tp, 8, 64);
        if ((lane & 15) == 0) tsum[r] = tp;
    }

    // ---- phase A3: weights -> W2S/W1S/vpart (L2-hot after first block on XCD)
    {
        #pragma unroll
        for (int k = 0; k < 2; ++k) {                // W2S[e*64+d] = W2[d][e]
            int fi = tid * 2 + k;                    // 0..1023
            int d = fi >> 4, e4 = (fi & 15) * 4;
            float4 v = ((const float4*)W2)[fi];
            W2S[(e4 + 0) * 64 + d] = f2bf(v.x);
            W2S[(e4 + 1) * 64 + d] = f2bf(v.y);
            W2S[(e4 + 2) * 64 + d] = f2bf(v.z);
            W2S[(e4 + 3) * 64 + d] = f2bf(v.w);
        }
        {                                            // W1S[e*32+f] = W1[f][e]
            int fi = tid;                            // 0..511
            int f = fi >> 4, e4 = (fi & 15) * 4;
            float4 v = ((const float4*)W1)[fi];
            W1S[(e4 + 0) * 32 + f] = f2bf(v.x);
            W1S[(e4 + 1) * 32 + f] = f2bf(v.y);
            W1S[(e4 + 2) * 32 + f] = f2bf(v.z);
            W1S[(e4 + 3) * 32 + f] = f2bf(v.w);
        }
        const int e = tid & 63, dg = tid >> 6;
        float s = 0.f;
        #pragma unroll
        for (int d0 = 0; d0 < 8; ++d0) {
            int d = dg * 8 + d0;
            s = fmaf(fmaxf(W4[d], 0.f), W3[d * DD + e], s);
        }
        vpart[dg * 64 + e] = s;
    }
    __syncthreads();                                 // adjS + weights ready

    // ---- phase B: ap tile = adjS(16 rows) @ prevS(16 cols), K=512
    f4 acc = {0.f, 0.f, 0.f, 0.f};
    #pragma unroll
    for (int ks = 0; ks < 16; ++ks) {
        s8 A  = *(const s8*)(&adjS[(16 * rh + l15) * AP + 32 * ks + 8 * g]);
        s8 Bf = *(const s8*)(&prevS[(16 * nt + l15) * AP + 32 * ks + 8 * g]);
        acc = __builtin_amdgcn_mfma_f32_16x16x32_bf16(A, Bf, acc, 0, 0, 0);
    }
    #pragma unroll
    for (int r = 0; r < 4; ++r)                      // C-layout -> PT (A-layout rows)
        PT[(16 * rh + 4 * g + r) * 72 + 16 * nt + l15] = f2bf(acc[r]);

    if (tid < 64) {                                  // v3 finalize
        float s = 0.f;
        #pragma unroll
        for (int dg = 0; dg < 8; ++dg) s += vpart[dg * 64 + tid];
        v3S[tid] = s;
    }
    __syncthreads();

    // ---- epilogue: o = t*v3 + nf@W1 + ap@W2, relu, store
    float vv = v3S[16 * nt + l15];
    f4 o;
    #pragma unroll
    for (int r = 0; r < 4; ++r) o[r] = tsum[16 * rh + 4 * g + r] * vv;

    {   // A1 = nf rows (fp32 -> bf16 inline)
        const float* nrow = nf + (i0 + 16 * rh + l15) * FN + 8 * g;
        float4 n0 = *(const float4*)(nrow);
        float4 n1 = *(const float4*)(nrow + 4);
        s8 A1;
        A1[0] = (short)f2bf(n0.x); A1[1] = (short)f2bf(n0.y);
        A1[2] = (short)f2bf(n0.z); A1[3] = (short)f2bf(n0.w);
        A1[4] = (short)f2bf(n1.x); A1[5] = (short)f2bf(n1.y);
        A1[6] = (short)f2bf(n1.z); A1[7] = (short)f2bf(n1.w);
        s8 B1 = *(const s8*)(&W1S[(16 * nt + l15) * 32 + 8 * g]);
        o = __builtin_amdgcn_mfma_f32_16x16x32_bf16(A1, B1, o, 0, 0, 0);
    }
    #pragma unroll
    for (int k2 = 0; k2 < 2; ++k2) {
        s8 A2 = *(const s8*)(&PT[(16 * rh + l15) * 72 + 32 * k2 + 8 * g]);
        s8 B2 = *(const s8*)(&W2S[(16 * nt + l15) * 64 + 32 * k2 + 8 * g]);
        o = __builtin_amdgcn_mfma_f32_16x16x32_bf16(A2, B2, o, 0, 0, 0);
    }

    #pragma unroll
    for (int r = 0; r < 4; ++r)
        out[(i0 + 16 * rh + 4 * g + r) * DD + 16 * nt + l15] = fmaxf(o[r], 0.f);
}

extern "C" void kernel_launch(void* const* d_in, const int* in_sizes, int n_in,
                              void* d_out, int out_size, void* d_ws, size_t ws_size,
                              hipStream_t stream) {
    const float* prev = (const float*)d_in[0];
    const float* adj  = (const float*)d_in[1];
    const float* nf   = (const float*)d_in[2];
    const float* ef   = (const float*)d_in[3];
    const float* W1   = (const float*)d_in[4];
    const float* W2   = (const float*)d_in[5];
    const float* W3   = (const float*)d_in[6];
    const float* W4   = (const float*)d_in[7];
    float* out = (float*)d_out;

    fused_kernel<<<dim3(256), dim3(512), 0, stream>>>(
        prev, adj, nf, ef, W1, W2, W3, W4, out);
}

// Round 15
// 95.497 us; speedup vs baseline: 1.0213x; 1.0213x over previous
//
#include <hip/hip_runtime.h>

#define NN 512
#define DD 64
#define FN 32
#define AP 520               // bf16 pitch (1040 B) for adjS/prevS rows

typedef unsigned short ushortT;
typedef __attribute__((ext_vector_type(4))) unsigned short us4;
typedef __attribute__((ext_vector_type(8))) short s8;     // 8 bf16 MFMA operand
typedef __attribute__((ext_vector_type(4))) float f4;     // MFMA accumulator

__device__ inline ushortT f2bf(float x) {
    unsigned u = __float_as_uint(x);
    return (ushortT)((u + 0x7FFFu + ((u >> 16) & 1u)) >> 16);   // RNE
}

// ---------------- Single fused kernel (R12 structure + hoisted adj/ef loads) ----------------
// 256 blocks (1/CU) x 512 thr (8 waves). Block owns 32 output rows of batch b.
// Phase order: issue adj/ef VMEM -> prev transpose (LDS) -> weights -> consume regs -> MFMA.
__global__ __launch_bounds__(512) void fused_kernel(
    const float* __restrict__ prev, const float* __restrict__ adj,
    const float* __restrict__ nf,   const float* __restrict__ ef,
    const float* __restrict__ W1,   const float* __restrict__ W2,
    const float* __restrict__ W3,   const float* __restrict__ W4,
    float* __restrict__ out)
{
    __shared__ __align__(16) ushortT adjS[32 * AP];   // 33280 B
    __shared__ __align__(16) ushortT prevS[64 * AP];  // 66560 B
    __shared__ __align__(16) ushortT PT[32 * 72];     //  4608 B
    __shared__ __align__(16) ushortT W2S[64 * 64];    //  8192 B
    __shared__ __align__(16) ushortT W1S[64 * 32];    //  4096 B
    __shared__ float vpart[8][64];                    //  2048 B
    __shared__ float v3S[64];
    __shared__ float tsum[32];

    const int tid  = threadIdx.x;
    const int lane = tid & 63;
    const int wv   = __builtin_amdgcn_readfirstlane(tid >> 6);  // 0..7
    const int blk  = blockIdx.x;
    const int i0   = blk * 32;
    const int b    = blk >> 4;           // 16 blocks per batch
    const int l15  = lane & 15, g = lane >> 4;
    const int rh   = wv >> 2, nt = wv & 3;

    // ---- phase A1a: ISSUE adj/ef loads early (named regs; consumed after A2/A3)
    const int r_ld = tid >> 4, c16 = tid & 15;
    const float4* ag = (const float4*)(adj + (i0 + r_ld) * NN + c16 * 32);
    const float4* eg = (const float4*)(ef  + (i0 + r_ld) * NN + c16 * 32);
    float4 av0 = ag[0], av1 = ag[1], av2 = ag[2], av3 = ag[3];
    float4 av4 = ag[4], av5 = ag[5], av6 = ag[6], av7 = ag[7];
    float4 ev0 = eg[0], ev1 = eg[1], ev2 = eg[2], ev3 = eg[3];
    float4 ev4 = eg[4], ev5 = eg[5], ev6 = eg[6], ev7 = eg[7];

    // ---- phase A2: prev[b] -> prevS transposed bf16 (overlaps adj/ef HBM latency)
    {
        const float4* pb = (const float4*)(prev + b * NN * DD);
        #pragma unroll
        for (int s = 0; s < 16; ++s) {
            int fidx = s * 512 + tid;            // 0..8191
            int j = fidx >> 4, d4 = (fidx & 15) * 4;
            float4 v = pb[fidx];
            prevS[(d4 + 0) * AP + j] = f2bf(v.x);
            prevS[(d4 + 1) * AP + j] = f2bf(v.y);
            prevS[(d4 + 2) * AP + j] = f2bf(v.z);
            prevS[(d4 + 3) * AP + j] = f2bf(v.w);
        }
    }

    // ---- phase A3: weights -> W2S/W1S/vpart
    {
        #pragma unroll
        for (int k = 0; k < 2; ++k) {            // W2S[e*64+d] = W2[d][e]
            int fi = tid * 2 + k;                // 0..1023
            int d = fi >> 4, e4 = (fi & 15) * 4;
            float4 v = ((const float4*)W2)[fi];
            W2S[(e4 + 0) * 64 + d] = f2bf(v.x);
            W2S[(e4 + 1) * 64 + d] = f2bf(v.y);
            W2S[(e4 + 2) * 64 + d] = f2bf(v.z);
            W2S[(e4 + 3) * 64 + d] = f2bf(v.w);
        }
        {                                        // W1S[e*32+f] = W1[f][e]
            int fi = tid;                        // 0..511
            int f = fi >> 4, e4 = (fi & 15) * 4;
            float4 v = ((const float4*)W1)[fi];
            W1S[(e4 + 0) * 32 + f] = f2bf(v.x);
            W1S[(e4 + 1) * 32 + f] = f2bf(v.y);
            W1S[(e4 + 2) * 32 + f] = f2bf(v.z);
            W1S[(e4 + 3) * 32 + f] = f2bf(v.w);
        }
        const int e = tid & 63, dg = tid >> 6;   // vpart: 8 d's per group
        float s = 0.f;
        #pragma unroll
        for (int d0 = 0; d0 < 8; ++d0) {
            int d = dg * 8 + d0;
            s = fmaf(fmaxf(W4[d], 0.f), W3[d * DD + e], s);
        }
        vpart[dg][e] = s;
    }

    // ---- phase A1b: consume regs -> t partial + adjS
    {
        float tp = av0.x*ev0.x + av0.y*ev0.y + av0.z*ev0.z + av0.w*ev0.w
                 + av1.x*ev1.x + av1.y*ev1.y + av1.z*ev1.z + av1.w*ev1.w
                 + av2.x*ev2.x + av2.y*ev2.y + av2.z*ev2.z + av2.w*ev2.w
                 + av3.x*ev3.x + av3.y*ev3.y + av3.z*ev3.z + av3.w*ev3.w
                 + av4.x*ev4.x + av4.y*ev4.y + av4.z*ev4.z + av4.w*ev4.w
                 + av5.x*ev5.x + av5.y*ev5.y + av5.z*ev5.z + av5.w*ev5.w
                 + av6.x*ev6.x + av6.y*ev6.y + av6.z*ev6.z + av6.w*ev6.w
                 + av7.x*ev7.x + av7.y*ev7.y + av7.z*ev7.z + av7.w*ev7.w;
        tp += __shfl_xor(tp, 1, 64);
        tp += __shfl_xor(tp, 2, 64);
        tp += __shfl_xor(tp, 4, 64);
        tp += __shfl_xor(tp, 8, 64);
        if ((lane & 15) == 0) tsum[r_ld] = tp;

        ushortT* arow = &adjS[r_ld * AP + c16 * 32];
        us4 o0 = { f2bf(av0.x), f2bf(av0.y), f2bf(av0.z), f2bf(av0.w) };
        us4 o1 = { f2bf(av1.x), f2bf(av1.y), f2bf(av1.z), f2bf(av1.w) };
        us4 o2 = { f2bf(av2.x), f2bf(av2.y), f2bf(av2.z), f2bf(av2.w) };
        us4 o3 = { f2bf(av3.x), f2bf(av3.y), f2bf(av3.z), f2bf(av3.w) };
        us4 o4 = { f2bf(av4.x), f2bf(av4.y), f2bf(av4.z), f2bf(av4.w) };
        us4 o5 = { f2bf(av5.x), f2bf(av5.y), f2bf(av5.z), f2bf(av5.w) };
        us4 o6 = { f2bf(av6.x), f2bf(av6.y), f2bf(av6.z), f2bf(av6.w) };
        us4 o7 = { f2bf(av7.x), f2bf(av7.y), f2bf(av7.z), f2bf(av7.w) };
        *(us4*)(arow + 0)  = o0;  *(us4*)(arow + 4)  = o1;
        *(us4*)(arow + 8)  = o2;  *(us4*)(arow + 12) = o3;
        *(us4*)(arow + 16) = o4;  *(us4*)(arow + 20) = o5;
        *(us4*)(arow + 24) = o6;  *(us4*)(arow + 28) = o7;
    }
    __syncthreads();                             // barrier 1

    // ---- phase B: ap tile = adjS(16 rows) @ prevS(16 cols), K=512, 16 k-steps
    f4 acc = {0.f, 0.f, 0.f, 0.f};
    #pragma unroll
    for (int ks = 0; ks < 16; ++ks) {
        s8 A  = *(const s8*)(&adjS[(16 * rh + l15) * AP + 32 * ks + 8 * g]);
        s8 Bf = *(const s8*)(&prevS[(16 * nt + l15) * AP + 32 * ks + 8 * g]);
        acc = __builtin_amdgcn_mfma_f32_16x16x32_bf16(A, Bf, acc, 0, 0, 0);
    }
    #pragma unroll
    for (int r = 0; r < 4; ++r)                  // C-layout -> PT (A-layout rows)
        PT[(16 * rh + 4 * g + r) * 72 + 16 * nt + l15] = f2bf(acc[r]);

    if (tid < 64) {                              // v3 finalize
        float s = 0.f;
        #pragma unroll
        for (int dg = 0; dg < 8; ++dg) s += vpart[dg][tid];
        v3S[tid] = s;
    }
    __syncthreads();                             // barrier 2

    // ---- epilogue: o = t*v3 + nf@W1 + ap@W2, relu, store
    float vv = v3S[16 * nt + l15];
    f4 o;
    #pragma unroll
    for (int r = 0; r < 4; ++r) o[r] = tsum[16 * rh + 4 * g + r] * vv;

    {   // A1 = nf rows (fp32 -> bf16 inline)
        const float* nrow = nf + (i0 + 16 * rh + l15) * FN + 8 * g;
        float4 n0 = *(const float4*)(nrow);
        float4 n1 = *(const float4*)(nrow + 4);
        s8 A1;
        A1[0] = (short)f2bf(n0.x); A1[1] = (short)f2bf(n0.y);
        A1[2] = (short)f2bf(n0.z); A1[3] = (short)f2bf(n0.w);
        A1[4] = (short)f2bf(n1.x); A1[5] = (short)f2bf(n1.y);
        A1[6] = (short)f2bf(n1.z); A1[7] = (short)f2bf(n1.w);
        s8 B1 = *(const s8*)(&W1S[(16 * nt + l15) * 32 + 8 * g]);
        o = __builtin_amdgcn_mfma_f32_16x16x32_bf16(A1, B1, o, 0, 0, 0);
    }
    #pragma unroll
    for (int k2 = 0; k2 < 2; ++k2) {
        s8 A2 = *(const s8*)(&PT[(16 * rh + l15) * 72 + 32 * k2 + 8 * g]);
        s8 B2 = *(const s8*)(&W2S[(16 * nt + l15) * 64 + 32 * k2 + 8 * g]);
        o = __builtin_amdgcn_mfma_f32_16x16x32_bf16(A2, B2, o, 0, 0, 0);
    }

    #pragma unroll
    for (int r = 0; r < 4; ++r)
        out[(i0 + 16 * rh + 4 * g + r) * DD + 16 * nt + l15] = fmaxf(o[r], 0.f);
}

extern "C" void kernel_launch(void* const* d_in, const int* in_sizes, int n_in,
                              void* d_out, int out_size, void* d_ws, size_t ws_size,
                              hipStream_t stream) {
    const float* prev = (const float*)d_in[0];
    const float* adj  = (const float*)d_in[1];
    const float* nf   = (const float*)d_in[2];
    const float* ef   = (const float*)d_in[3];
    const float* W1   = (const float*)d_in[4];
    const float* W2   = (const float*)d_in[5];
    const float* W3   = (const float*)d_in[6];
    const float* W4   = (const float*)d_in[7];
    float* out = (float*)d_out;

    fused_kernel<<<dim3(256), dim3(512), 0, stream>>>(
        prev, adj, nf, ef, W1, W2, W3, W4, out);
}